// Round 9
// baseline (23.521 us; speedup 1.0000x reference)
//
#include <hip/hip_runtime.h>

#define BB 8192
#define SEQF 2560      // floats per sequence (512*5)

typedef float v2f __attribute__((ext_vector_type(2)));

__device__ __forceinline__ float rfl(float x) {
    return __int_as_float(__builtin_amdgcn_readfirstlane(__float_as_int(x)));
}
__device__ __forceinline__ v2f vsplat(float x) { return (v2f){x, x}; }

// 512 waves total (256 blocks x 2 waves, 1 block/CU). Each wave owns 16
// consecutive sequences (160 KB) and streams them sequentially over 8
// double-buffered iterations (<=40 KB contiguous in flight per wave) --
// few, deep, address-ordered streams for DRAM row locality.
// Per iteration: wave = 2 sequences (lanes 0-31 seq A, 32-63 seq B), lane owns
// 16 timesteps; packed-f32 3x3 transfer matrices; shared 5-level suffix tree;
// exact power-of-two renorm; bias e^-2 folded into E (compensated exactly).
__global__ __launch_bounds__(128, 1) void crf_fused(const float* __restrict__ feats,
                                                    const float* __restrict__ trans,
                                                    float* __restrict__ out) {
    const int tid  = threadIdx.x;
    const int lane = tid & 63;
    const int half = lane >> 5;      // which sequence of the current pair
    const int cpos = lane & 31;      // chunk index within the sequence
    const int wv   = tid >> 6;
    const int bid  = blockIdx.x;                  // 0..255
    const int xbid = (bid & 7) * 32 + (bid >> 3); // XCD-contiguous address chunks
    const int gw   = xbid * 2 + wv;               // 0..511
    const int sbase = gw * 16;                    // 16 sequences per wave

    // ---- uniform transition factors -> SGPRs; bias e^-2 folded in ----
    const float BIAS = 0.13533528323661270f;   // e^-2
    const float E00=rfl(__expf(trans[0])*BIAS),  E01=rfl(__expf(trans[1])*BIAS),  E02=rfl(__expf(trans[2])*BIAS);
    const float E10=rfl(__expf(trans[5])*BIAS),  E11=rfl(__expf(trans[6])*BIAS),  E12=rfl(__expf(trans[7])*BIAS);
    const float E20=rfl(__expf(trans[10])*BIAS), E21=rfl(__expf(trans[11])*BIAS), E22=rfl(__expf(trans[12])*BIAS);
    const float C0 =rfl(__expf(trans[3])*BIAS),  C1 =rfl(__expf(trans[8])*BIAS),  C2 =rfl(__expf(trans[13])*BIAS);
    const float S0 =rfl(__expf(trans[20])), S1 =rfl(__expf(trans[21])), S2 =rfl(__expf(trans[22]));

    const v2f E00p=vsplat(E00), E01p=vsplat(E01), E02p=vsplat(E02);
    const v2f E10p=vsplat(E10), E11p=vsplat(E11), E12p=vsplat(E12);
    const v2f E20p=vsplat(E20), E21p=vsplat(E21), E22p=vsplat(E22);

    // first-step factor: chunk 0 of each sequence starts from the START column
    const bool c0 = (cpos == 0);
    const v2f GA0 = c0 ? vsplat(C0) : (v2f){E00, E01};
    const v2f GA1 = c0 ? vsplat(C1) : (v2f){E10, E11};
    const v2f GA2 = c0 ? vsplat(C2) : (v2f){E20, E21};
    const float GB0 = c0 ? C0 : E02;
    const float GB1 = c0 ? C1 : E12;
    const float GB2 = c0 ? C2 : E22;

    float4 A[20], B[20];

    // issue the 20 loads for the pair starting at sequence s0 (320 B/lane)
#define LOADP(R, s0) do {                                                     \
        const float4* _p = (const float4*)(feats + (size_t)((s0) + half) * SEQF) + cpos * 20; \
        _Pragma("unroll")                                                     \
        for (int _k = 0; _k < 20; ++_k) (R)[_k] = _p[_k];                     \
        __builtin_amdgcn_sched_barrier(0);                                    \
    } while (0)

#define CRF_STEP(FA, FB, FC) do {                                   \
        float e0 = __expf(FA), e1 = __expf(FB), e2 = __expf(FC);    \
        v2f NA0 = vsplat(e0) * (E00p*MA0 + E01p*MA1 + E02p*MA2);    \
        v2f NA1 = vsplat(e1) * (E10p*MA0 + E11p*MA1 + E12p*MA2);    \
        v2f NA2 = vsplat(e2) * (E20p*MA0 + E21p*MA1 + E22p*MA2);    \
        float NB0 = e0 * (E00*MB0 + E01*MB1 + E02*MB2);             \
        float NB1 = e1 * (E10*MB0 + E11*MB1 + E12*MB2);             \
        float NB2 = e2 * (E20*MB0 + E21*MB1 + E22*MB2);             \
        MA0=NA0; MA1=NA1; MA2=NA2; MB0=NB0; MB1=NB1; MB2=NB2;       \
    } while (0)

#define CRF_RENORM() do {                                           \
        v2f mp = __builtin_elementwise_max(__builtin_elementwise_max(MA0, MA1), MA2); \
        float mm = fmaxf(fmaxf(mp.x, mp.y), fmaxf(fmaxf(MB0, MB1), MB2)); \
        mm = fmaxf(mm, 1e-30f);                                     \
        int ee = (int)((__float_as_uint(mm) >> 23) & 0xffu) - 127;  \
        float sc = __uint_as_float((unsigned)(127 - ee) << 23);     \
        ls += (float)ee;                                            \
        v2f scp = vsplat(sc);                                       \
        MA0*=scp; MA1*=scp; MA2*=scp; MB0*=sc; MB1*=sc; MB2*=sc;    \
    } while (0)

#define TREE_LEVEL(D, RN) do {                                      \
        v2f PA0, PA1, PA2;                                          \
        PA0.x=__shfl_down(MA0.x,D); PA0.y=__shfl_down(MA0.y,D);     \
        PA1.x=__shfl_down(MA1.x,D); PA1.y=__shfl_down(MA1.y,D);     \
        PA2.x=__shfl_down(MA2.x,D); PA2.y=__shfl_down(MA2.y,D);     \
        float PB0=__shfl_down(MB0,D), PB1=__shfl_down(MB1,D), PB2=__shfl_down(MB2,D); \
        float Pls=__shfl_down(ls, D);                               \
        v2f NA0 = vsplat(PA0.x)*MA0 + vsplat(PA0.y)*MA1 + vsplat(PB0)*MA2; \
        v2f NA1 = vsplat(PA1.x)*MA0 + vsplat(PA1.y)*MA1 + vsplat(PB1)*MA2; \
        v2f NA2 = vsplat(PA2.x)*MA0 + vsplat(PA2.y)*MA1 + vsplat(PB2)*MA2; \
        float NB0 = PA0.x*MB0 + PA0.y*MB1 + PB0*MB2;                \
        float NB1 = PA1.x*MB0 + PA1.y*MB1 + PB1*MB2;                \
        float NB2 = PA2.x*MB0 + PA2.y*MB1 + PB2*MB2;                \
        MA0=NA0; MA1=NA1; MA2=NA2; MB0=NB0; MB1=NB1; MB2=NB2;       \
        ls += Pls;                                                  \
        if (RN) CRF_RENORM();                                       \
    } while (0)

    // full per-pair scan over register array Q[20] (floats 5t..5t+2 = step t)
#define COMPUTE(Q, S0) do {                                         \
        v2f MA0, MA1, MA2;                                          \
        float MB0, MB1, MB2;                                        \
        float ls = 0.0f;                                            \
        {   float e0 = __expf((Q)[0].x), e1 = __expf((Q)[0].y), e2 = __expf((Q)[0].z); \
            MA0 = vsplat(e0) * GA0;  MB0 = e0 * GB0;                \
            MA1 = vsplat(e1) * GA1;  MB1 = e1 * GB1;                \
            MA2 = vsplat(e2) * GA2;  MB2 = e2 * GB2;                \
        }                                                           \
        CRF_STEP((Q)[1].y,  (Q)[1].z,  (Q)[1].w);                   \
        CRF_STEP((Q)[2].z,  (Q)[2].w,  (Q)[3].x);                   \
        CRF_STEP((Q)[3].w,  (Q)[4].x,  (Q)[4].y);                   \
        CRF_STEP((Q)[5].x,  (Q)[5].y,  (Q)[5].z);                   \
        CRF_STEP((Q)[6].y,  (Q)[6].z,  (Q)[6].w);                   \
        CRF_STEP((Q)[7].z,  (Q)[7].w,  (Q)[8].x);                   \
        CRF_STEP((Q)[8].w,  (Q)[9].x,  (Q)[9].y);                   \
        CRF_STEP((Q)[10].x, (Q)[10].y, (Q)[10].z);                  \
        CRF_STEP((Q)[11].y, (Q)[11].z, (Q)[11].w);                  \
        CRF_STEP((Q)[12].z, (Q)[12].w, (Q)[13].x);                  \
        CRF_STEP((Q)[13].w, (Q)[14].x, (Q)[14].y);                  \
        CRF_STEP((Q)[15].x, (Q)[15].y, (Q)[15].z);                  \
        CRF_STEP((Q)[16].y, (Q)[16].z, (Q)[16].w);                  \
        CRF_STEP((Q)[17].z, (Q)[17].w, (Q)[18].x);                  \
        CRF_STEP((Q)[18].w, (Q)[19].x, (Q)[19].y);                  \
        CRF_RENORM();                                               \
        TREE_LEVEL(1, 0);                                           \
        TREE_LEVEL(2, 0);                                           \
        TREE_LEVEL(4, 1);                                           \
        TREE_LEVEL(8, 0);                                           \
        TREE_LEVEL(16, 1);                                          \
        float r = S0_*MA0.x + S1_*MA1.x + S2_*MA2.x;                \
        float res = __logf(r) + ls * 0.69314718055994531f + 1024.0f;\
        if (cpos == 0) out[(S0) + half] = res;                      \
    } while (0)

    const float S0_ = S0, S1_ = S1, S2_ = S2;

    // ---- 8 double-buffered iterations over the wave's 16-sequence region ----
    LOADP(A, sbase);
    #pragma unroll
    for (int it = 0; it < 8; it += 2) {
        LOADP(B, sbase + (it + 1) * 2);
        COMPUTE(A, sbase + it * 2);
        if (it + 2 < 8) LOADP(A, sbase + (it + 2) * 2);
        COMPUTE(B, sbase + (it + 1) * 2);
    }

#undef LOADP
#undef CRF_STEP
#undef CRF_RENORM
#undef TREE_LEVEL
#undef COMPUTE
}

extern "C" void kernel_launch(void* const* d_in, const int* in_sizes, int n_in,
                              void* d_out, int out_size, void* d_ws, size_t ws_size,
                              hipStream_t stream) {
    const float* feats = (const float*)d_in[0];
    const float* trans = (const float*)d_in[1];
    float* out = (float*)d_out;
    (void)d_ws; (void)ws_size;

    crf_fused<<<256, 128, 0, stream>>>(feats, trans, out);
}